// Round 15
// baseline (988.806 us; speedup 1.0000x reference)
//
#include <hip/hip_runtime.h>
#include <math.h>

// Problem constants (from reference)
#define NROWS 18432
#define IN_DIM 1024
#define HID_DIM 4096
#define OUT_DIM 4096
#define NTN 16    // 4096/256 column tiles
#define BM  192   // 18432/192=96 -> 1536 blocks = exactly 6 rounds on 256 CUs (R14 win)

typedef __attribute__((ext_vector_type(8)))  short bf16x8;
typedef __attribute__((ext_vector_type(16))) float f32x16;

typedef const __attribute__((address_space(1))) char gchar;
typedef __attribute__((address_space(3))) char lchar;

__device__ __forceinline__ unsigned short f2bf(float f) {
    union { float f; unsigned u; } v; v.f = f;
    unsigned r = v.u + 0x7fffu + ((v.u >> 16) & 1u);  // RNE
    return (unsigned short)(r >> 16);
}

__device__ __forceinline__ f32x16 MFMA32(bf16x8 a, bf16x8 b, f32x16 c) {
    return __builtin_amdgcn_mfma_f32_32x32x16_bf16(a, b, c, 0, 0, 0);
}

// ---------------- conversion kernels ----------------

__global__ void cvt_f32_bf16_k(const float4* __restrict__ in, uint4* __restrict__ out, int nvec) {
    int i = blockIdx.x * blockDim.x + threadIdx.x;
    if (i >= nvec) return;
    float4 a = in[2 * i], b = in[2 * i + 1];
    union { unsigned short s[8]; uint4 v; } o;
    o.s[0] = f2bf(a.x); o.s[1] = f2bf(a.y); o.s[2] = f2bf(a.z); o.s[3] = f2bf(a.w);
    o.s[4] = f2bf(b.x); o.s[5] = f2bf(b.y); o.s[6] = f2bf(b.z); o.s[7] = f2bf(b.w);
    out[i] = o.v;
}

// int8 values harness-materialized as int32; exact in bf16
__global__ void cvt_i32_bf16_k(const int4* __restrict__ in, uint4* __restrict__ out, int nvec) {
    int i = blockIdx.x * blockDim.x + threadIdx.x;
    if (i >= nvec) return;
    int4 a = in[2 * i], b = in[2 * i + 1];
    union { unsigned short s[8]; uint4 v; } o;
    o.s[0] = f2bf((float)a.x); o.s[1] = f2bf((float)a.y);
    o.s[2] = f2bf((float)a.z); o.s[3] = f2bf((float)a.w);
    o.s[4] = f2bf((float)b.x); o.s[5] = f2bf((float)b.y);
    o.s[6] = f2bf((float)b.z); o.s[7] = f2bf((float)b.w);
    out[i] = o.v;
}

// ---- 192x256 GEMM, 32x32x16 MFMA, FRAGMENT-CONTIGUOUS LDS, R14 stage/wait ledger ----
// Shape: 32x32x16 runs at 2495 vs 2075 TF (m119, +20%); R11 verified its operand + C/D layouts
// (refcheck passed) but row-major LDS gave 5.7e7 bank conflicts (rows r,r+8 alias; slot-XOR
// can't fix 32 rows over 8 slots). Fix: LDS holds each 32-row x 16-k fragment as 1KB
// CONTIGUOUS; lane l reads frag_base + l*16 (linear = 0 conflicts by construction, same
// pattern as the gload_lds write). STAGE inverts the layout on the per-lane GLOBAL address
// (rule 21): wave wid stages fragment UN*8+wid; lane supplies (row=rb*32+(l&31),
// k=kf*16+(l>>5)*8). A region/buf = 24KB (frags (rb0..5,kf0..3)), B = 32KB (cb0..7,kf0..3).
// Iter = 2 K64-tiles, 6 phases (3/tile: rb0,rb1,rb2); 8 MFMA_32x32/phase; per-wave out 96x64
// = acc[3]x2 f32x16. Stage units/iter = 14, order IDENTICAL to R14: A(b)@P0, B(a+2)@P1/P2,
// A(a+2)@P3, B(b+2)@P4/P5; waits vmcnt(4)@P2 (11 outstanding -> drains B(b)+A(b)) and @P5
// (drains tile a+2); tail v0@P2. WAR death-windows all >=1 barrier (checked per-region).
// EPI==0: bf16 gelu(acc*sc+bi); EPI==1: f32 acc*sc+bi. Output row-stride hardcoded 4096.
template<int EPI>
__global__ __launch_bounds__(512, 2)
void gemmfc(const unsigned short* __restrict__ A, const unsigned short* __restrict__ B,
            const float* __restrict__ scale, const float* __restrict__ bias,
            void* __restrict__ Cout, int K) {
    extern __shared__ __align__(16) char sm[];   // 114688 bytes (2 bufs x 56KB)

    const int tid  = threadIdx.x;
    const int lane = tid & 63;
    const int wid  = tid >> 6;
    const int wm   = wid >> 2, wn = wid & 3;

    // T1: bijective XCD swizzle (m204)
    const int nwg  = gridDim.x;
    const int q    = nwg >> 3, r = nwg & 7;
    const int xcd  = blockIdx.x & 7, bidx = blockIdx.x >> 3;
    const int swz  = xcd * q + (xcd < r ? xcd : r) + bidx;
    const int tm   = swz / NTN, tn = swz % NTN;

    const size_t rowbytes = (size_t)K * 2;
    const char* Ag = (const char*)A + (size_t)tm * BM * rowbytes;
    const char* Bg = (const char*)B + (size_t)tn * 256 * rowbytes;

    const int l32 = lane & 31;

    f32x16 acc0[3] = {};   // [rb local] x col-block wn*2+0
    f32x16 acc1[3] = {};   // [rb local] x col-block wn*2+1
    bf16x8 aq[4], b0[4], b1[4];

    const int NIT = K >> 7;   // iterations (2 K-tiles of 64)
    const int lb16 = lane << 4;

// stage one 8KB unit = 8 fragments; wave wid stages fragment (UN*8+wid) of region at REGOFF.
// LDS dest: uniform base (REGOFF + fi*1024) + lane*16 (linear). Global source per-lane (rule 21).
#define STAGE(GB, REGOFF, UN, TILE) { \
    const int fi_ = ((UN) << 3) + wid; \
    const int rb_ = fi_ >> 2, kf_ = fi_ & 3; \
    __builtin_amdgcn_global_load_lds( \
        (gchar*)((GB) + (size_t)(rb_ * 32 + l32) * rowbytes + ((size_t)(TILE) << 7) \
                 + (size_t)((kf_ << 5) + ((lane >> 5) << 4))), \
        (lchar*)(sm + (REGOFF) + (fi_ << 10) + lb16), 16, 0, 0); \
}

// fragment reads: linear, wave-uniform base + lane*16 (0 conflicts)
#define RA(BUFOFF, I, KF) (*(const bf16x8*)(sm + (BUFOFF) + (((wm * 3 + (I)) * 4 + (KF)) << 10) + lb16))
#define RB(BUFOFF, J, KF) (*(const bf16x8*)(sm + (BUFOFF) + 24576 + (((wn * 2 + (J)) * 4 + (KF)) << 10) + lb16))

// one rb-row-block x both col-blocks x K=64: 8 MFMA_32x32x16
#define MF(I) { __builtin_amdgcn_s_setprio(1); \
    _Pragma("unroll") for (int kf_ = 0; kf_ < 4; ++kf_) acc0[I] = MFMA32(aq[kf_], b0[kf_], acc0[I]); \
    _Pragma("unroll") for (int kf_ = 0; kf_ < 4; ++kf_) acc1[I] = MFMA32(aq[kf_], b1[kf_], acc1[I]); \
    __builtin_amdgcn_s_setprio(0); }

#define SFENCE __builtin_amdgcn_sched_barrier(0)
#define WAITV4 { SFENCE; asm volatile("s_waitcnt vmcnt(4)"); SFENCE; }
#define WAITV0 { SFENCE; asm volatile("s_waitcnt vmcnt(0)"); SFENCE; }
#define BARR   { SFENCE; __builtin_amdgcn_s_barrier(); SFENCE; }

#define BUF1 57344

    // prologue: A(0)u0-2 + B(0)u0-3 -> buf0, B(1)u0-3 -> buf1 (11 issues);
    // vmcnt(4) drains the 7 oldest = A(0)+B(0); B(1) stays in flight. A(1) staged at j=0 P0.
    STAGE(Ag, 0,            0, 0); STAGE(Ag, 0,            1, 0); STAGE(Ag, 0,            2, 0);
    STAGE(Bg, 24576,        0, 0); STAGE(Bg, 24576,        1, 0);
    STAGE(Bg, 24576,        2, 0); STAGE(Bg, 24576,        3, 0);
    STAGE(Bg, BUF1 + 24576, 0, 1); STAGE(Bg, BUF1 + 24576, 1, 1);
    STAGE(Bg, BUF1 + 24576, 2, 1); STAGE(Bg, BUF1 + 24576, 3, 1);
    WAITV4; BARR;

    for (int j = 0; j < NIT; ++j) {
        const int  t1 = 2 * j + 1, ta2 = 2 * j + 2, tb2 = 2 * j + 3;
        const bool lastj = (j == NIT - 1);

        // ---- tile a (buf0) ----
        // P0: read rb0 + all B; stage A(b)u0-2 -> buf1
        #pragma unroll
        for (int kf = 0; kf < 4; ++kf) {
            aq[kf] = RA(0, 0, kf); b0[kf] = RB(0, 0, kf); b1[kf] = RB(0, 1, kf);
        }
        STAGE(Ag, BUF1, 0, t1); STAGE(Ag, BUF1, 1, t1); STAGE(Ag, BUF1, 2, t1);
        BARR; MF(0);
        // P1: read rb1; stage B(a+2)u0,u1 -> buf0
        #pragma unroll
        for (int kf = 0; kf < 4; ++kf) aq[kf] = RA(0, 1, kf);
        if (!lastj) { STAGE(Bg, 24576, 0, ta2); STAGE(Bg, 24576, 1, ta2); }
        BARR; MF(1);
        // P2: read rb2; stage B(a+2)u2,u3; counted wait #1 (drains B(b)+A(b))
        #pragma unroll
        for (int kf = 0; kf < 4; ++kf) aq[kf] = RA(0, 2, kf);
        if (!lastj) { STAGE(Bg, 24576, 2, ta2); STAGE(Bg, 24576, 3, ta2); WAITV4; }
        else        { WAITV0; }
        BARR; MF(2);

        // ---- tile b (buf1) ----
        // P3: read rb0 + all B; stage A(a+2)u0-2 -> buf0
        #pragma unroll
        for (int kf = 0; kf < 4; ++kf) {
            aq[kf] = RA(BUF1, 0, kf); b0[kf] = RB(BUF1, 0, kf); b1[kf] = RB(BUF1, 1, kf);
        }
        if (!lastj) { STAGE(Ag, 0, 0, ta2); STAGE(Ag, 0, 1, ta2); STAGE(Ag, 0, 2, ta2); }
        BARR; MF(0);
        // P4: read rb1; stage B(b+2)u0,u1 -> buf1
        #pragma unroll
        for (int kf = 0; kf < 4; ++kf) aq[kf] = RA(BUF1, 1, kf);
        if (!lastj) { STAGE(Bg, BUF1 + 24576, 0, tb2); STAGE(Bg, BUF1 + 24576, 1, tb2); }
        BARR; MF(1);
        // P5: read rb2; stage B(b+2)u2,u3; counted wait #2 (drains tile a+2)
        #pragma unroll
        for (int kf = 0; kf < 4; ++kf) aq[kf] = RA(BUF1, 2, kf);
        if (!lastj) { STAGE(Bg, BUF1 + 24576, 2, tb2); STAGE(Bg, BUF1 + 24576, 3, tb2); WAITV4; }
        BARR; MF(2);
    }
#undef STAGE
#undef RA
#undef RB
#undef MF
#undef SFENCE
#undef WAITV4
#undef WAITV0
#undef BARR
#undef BUF1

    // epilogue: 32x32 C/D layout col=lane&31, row=(reg&3)+8*(reg>>2)+4*(lane>>5)  [m74/m101, R11]
    const int rbase = (lane >> 5) << 2;
    #pragma unroll
    for (int i = 0; i < 3; ++i)
        #pragma unroll
        for (int jj = 0; jj < 2; ++jj) {
            const f32x16* a = (jj == 0) ? &acc0[i] : &acc1[i];
            const int col = tn * 256 + wn * 64 + jj * 32 + l32;
            const float sc = scale[col];
            const float bi = bias[col];
            const int r0 = tm * BM + wm * 96 + i * 32 + rbase;
            #pragma unroll
            for (int rg = 0; rg < 4; ++rg)
                #pragma unroll
                for (int rr = 0; rr < 4; ++rr) {
                    float v = (*a)[rg * 4 + rr] * sc + bi;
                    const int row = r0 + rg * 8 + rr;
                    if (EPI == 0) {
                        float g = 0.5f * v * (1.0f + erff(v * 0.70710678118654752f));
                        ((unsigned short*)Cout)[(size_t)row * 4096 + col] = f2bf(g);
                    } else {
                        ((float*)Cout)[(size_t)row * 4096 + col] = v;
                    }
                }
        }
}

extern "C" void kernel_launch(void* const* d_in, const int* in_sizes, int n_in,
                              void* d_out, int out_size, void* d_ws, size_t ws_size,
                              hipStream_t stream) {
    const float* x   = (const float*)d_in[0];
    const int*   w1q = (const int*)d_in[1];
    const float* s1  = (const float*)d_in[2];
    const float* b1  = (const float*)d_in[3];
    const int*   w2q = (const int*)d_in[4];
    const float* s2  = (const float*)d_in[5];
    const float* b2  = (const float*)d_in[6];
    float*       out = (float*)d_out;

    // allow 112 KiB dynamic LDS (idempotent, not a stream op)
    hipFuncSetAttribute((const void*)gemmfc<0>, hipFuncAttributeMaxDynamicSharedMemorySize, 114688);
    hipFuncSetAttribute((const void*)gemmfc<1>, hipFuncAttributeMaxDynamicSharedMemorySize, 114688);

    char* ws = (char*)d_ws;
    const size_t XBF  = (size_t)NROWS   * IN_DIM  * 2;
    const size_t W1BF = (size_t)HID_DIM * IN_DIM  * 2;
    const size_t W2BF = (size_t)OUT_DIM * HID_DIM * 2;
    const size_t FIXED = XBF + W1BF + W2BF;

    unsigned short* xbf  = (unsigned short*)ws;
    unsigned short* w1bf = (unsigned short*)(ws + XBF);
    unsigned short* w2bf = (unsigned short*)(ws + XBF + W1BF);
    unsigned short* hbuf = (unsigned short*)(ws + FIXED);

    {
        int nvx = NROWS * IN_DIM / 8;
        cvt_f32_bf16_k<<<(nvx + 255) / 256, 256, 0, stream>>>((const float4*)x, (uint4*)xbf, nvx);
        int nv1 = HID_DIM * IN_DIM / 8;
        cvt_i32_bf16_k<<<(nv1 + 255) / 256, 256, 0, stream>>>((const int4*)w1q, (uint4*)w1bf, nv1);
        int nv2 = OUT_DIM * HID_DIM / 8;
        cvt_i32_bf16_k<<<(nv2 + 255) / 256, 256, 0, stream>>>((const int4*)w2q, (uint4*)w2bf, nv2);
    }

    // chunk M (multiples of BM) so h fits in remaining workspace
    size_t avail = (ws_size > FIXED) ? (ws_size - FIXED) : 0;
    long rp = (long)(avail / ((size_t)HID_DIM * 2));
    rp = (rp / BM) * BM;
    if (rp > NROWS) rp = NROWS;
    if (rp < BM)    rp = BM;

    for (int r0 = 0; r0 < NROWS; r0 += (int)rp) {
        int rows = (int)(((long)(NROWS - r0) < rp) ? (NROWS - r0) : rp);
        dim3 g(NTN * (rows / BM));
        gemmfc<0><<<g, 512, 114688, stream>>>(xbf + (size_t)r0 * IN_DIM, w1bf, s1, b1,
                                              (void*)hbuf, IN_DIM);
        gemmfc<1><<<g, 512, 114688, stream>>>(hbuf, w2bf, s2, b2,
                                              (void*)(out + (size_t)r0 * OUT_DIM), HID_DIM);
    }
    (void)in_sizes; (void)n_in; (void)out_size;
}

// Round 16
// 830.172 us; speedup vs baseline: 1.1911x; 1.1911x over previous
//
#include <hip/hip_runtime.h>
#include <math.h>

// Problem constants (from reference)
#define NROWS 18432
#define IN_DIM 1024
#define HID_DIM 4096
#define OUT_DIM 4096
#define NTN 16    // 4096/256 column tiles
#define BM  192   // 18432/192=96 -> 1536 blocks = exactly 6 rounds on 256 CUs (R14 win)

typedef __attribute__((ext_vector_type(8))) short bf16x8;
typedef __attribute__((ext_vector_type(4))) float f32x4;

typedef const __attribute__((address_space(1))) char gchar;
typedef __attribute__((address_space(3))) char lchar;

__device__ __forceinline__ unsigned short f2bf(float f) {
    union { float f; unsigned u; } v; v.f = f;
    unsigned r = v.u + 0x7fffu + ((v.u >> 16) & 1u);  // RNE
    return (unsigned short)(r >> 16);
}

__device__ __forceinline__ f32x4 MFMA16(bf16x8 a, bf16x8 b, f32x4 c) {
    return __builtin_amdgcn_mfma_f32_16x16x32_bf16(a, b, c, 0, 0, 0);
}

// ---------------- conversion kernels ----------------

__global__ void cvt_f32_bf16_k(const float4* __restrict__ in, uint4* __restrict__ out, int nvec) {
    int i = blockIdx.x * blockDim.x + threadIdx.x;
    if (i >= nvec) return;
    float4 a = in[2 * i], b = in[2 * i + 1];
    union { unsigned short s[8]; uint4 v; } o;
    o.s[0] = f2bf(a.x); o.s[1] = f2bf(a.y); o.s[2] = f2bf(a.z); o.s[3] = f2bf(a.w);
    o.s[4] = f2bf(b.x); o.s[5] = f2bf(b.y); o.s[6] = f2bf(b.z); o.s[7] = f2bf(b.w);
    out[i] = o.v;
}

// int8 values harness-materialized as int32; exact in bf16
__global__ void cvt_i32_bf16_k(const int4* __restrict__ in, uint4* __restrict__ out, int nvec) {
    int i = blockIdx.x * blockDim.x + threadIdx.x;
    if (i >= nvec) return;
    int4 a = in[2 * i], b = in[2 * i + 1];
    union { unsigned short s[8]; uint4 v; } o;
    o.s[0] = f2bf((float)a.x); o.s[1] = f2bf((float)a.y);
    o.s[2] = f2bf((float)a.z); o.s[3] = f2bf((float)a.w);
    o.s[4] = f2bf((float)b.x); o.s[5] = f2bf((float)b.y);
    o.s[6] = f2bf((float)b.z); o.s[7] = f2bf((float)b.w);
    out[i] = o.v;
}

// -------- 192x256 6-phase GEMM (R14 with zero-read phases merged), BK=64, 2 K-tiles/iter -----
// R14 (8-phase, 802us, MfmaUtil 56.7%) is the best-measured config; R15's 32x32 fragment-LDS
// regressed (global over-fetch from 32B/row staging + 4-deep dependent MFMA chains).
// Delta vs R14: P2+P3 and P6+P7 merged (those were zero-read / read-light phases) -> 6 barriers
// per iter instead of 8, 24-MFMA clusters on the merged phases. ISSUE ORDER AND WAIT POSITIONS
// ARE BIT-IDENTICAL to R14 (traced: at each WAITV4 outstanding=11, drains 7 oldest = exactly
// tile b resp. tile a+2; remaining 4 = newest B stages). WAR death-windows unchanged.
// 8 waves (2Mx4N), per-wave 96x64 (acc[6][4]). LDS: 2 bufs x 56KB {A 24KB = 3x8KB units,
// B 32KB = 4x8KB units}; buf0 @0 (even tiles), buf1 @57344 (odd).
// Swizzle: slot (ks*4+cgi)^(l16&7) on reads; inverse on stage source (rule 21); 0-conflict.
// EPI==0: bf16 gelu(acc*sc+bi); EPI==1: f32 acc*sc+bi. Output row-stride hardcoded 4096.
template<int EPI>
__global__ __launch_bounds__(512, 2)
void gemm192(const unsigned short* __restrict__ A, const unsigned short* __restrict__ B,
             const float* __restrict__ scale, const float* __restrict__ bias,
             void* __restrict__ Cout, int K) {
    extern __shared__ __align__(16) char sm[];   // 114688 bytes dynamic

    const int tid  = threadIdx.x;
    const int lane = tid & 63;
    const int wid  = tid >> 6;
    const int wm   = wid >> 2, wn = wid & 3;

    // T1: bijective XCD swizzle (m204); nwg = 1536 (multiple of 8)
    const int nwg  = gridDim.x;
    const int q    = nwg >> 3, r = nwg & 7;
    const int xcd  = blockIdx.x & 7, bidx = blockIdx.x >> 3;
    const int swz  = xcd * q + (xcd < r ? xcd : r) + bidx;
    const int tm   = swz / NTN, tn = swz % NTN;

    const size_t rowbytes = (size_t)K * 2;
    const char* Ag = (const char*)A + (size_t)tm * BM * rowbytes;
    const char* Bg = (const char*)B + (size_t)tn * 256 * rowbytes;

    const int l16 = lane & 15;
    const int cgi = lane >> 4;
    const int sw  = l16 & 7;
    const int c0  = ((cgi       ^ sw) << 4);   // swizzled byte-slot, k-step 0
    const int c1  = (((4 | cgi) ^ sw) << 4);   // swizzled byte-slot, k-step 1

    f32x4  acc[6][4] = {};
    bf16x8 aq[3][2], bn0[2][2], bn1[2][2];

    const int NIT = K >> 7;   // iterations (2 K-tiles of 64 each)

// stage one 8KB unit UN of region at LDSOFF (A: UN 0-2 covers rows 0-191; B: UN 0-3 rows 0-255)
// LDS dest linear; global source pre-inverse-swizzled (rule 21).
#define STAGE(GB, LDSOFF, UN, TILE) { \
    const int po_ = ((UN) << 13) + (tid << 4); \
    const int pr_ = po_ >> 7; \
    const int pc_ = (po_ & 127) ^ ((pr_ & 7) << 4); \
    __builtin_amdgcn_global_load_lds( \
        (gchar*)((GB) + (size_t)pr_ * rowbytes + ((size_t)(TILE) << 7) + (size_t)pc_), \
        (lchar*)(sm + (LDSOFF) + po_), 16, 0, 0); \
}

// A frags for 48-row quadrant MH: rows wm*96 + MH*48 + mm*16 + l16 (row&7 == l16&7)
#define READ_A(BUFOFF, MH) { const char* Ab_ = sm + (BUFOFF); \
    _Pragma("unroll") for (int mm_ = 0; mm_ < 3; ++mm_) { \
        const int ro_ = (wm * 96 + (MH) * 48 + mm_ * 16 + l16) << 7; \
        aq[mm_][0] = *(const bf16x8*)(Ab_ + ro_ + c0); \
        aq[mm_][1] = *(const bf16x8*)(Ab_ + ro_ + c1); } }

// B frags for 32-col half NH of this wave's 64-col strip
#define READ_B(BUFOFF, NH, DST) { const char* Bb_ = sm + (BUFOFF) + 24576; \
    _Pragma("unroll") for (int nn_ = 0; nn_ < 2; ++nn_) { \
        const int ro_ = ((wn >> 1) * 128 + (wn & 1) * 64 + (NH) * 32 + nn_ * 16 + l16) << 7; \
        DST[nn_][0] = *(const bf16x8*)(Bb_ + ro_ + c0); \
        DST[nn_][1] = *(const bf16x8*)(Bb_ + ro_ + c1); } }

// one quadrant x K=64: 3 mm x 2 nn x 2 ks = 12 MFMA
#define MF(MH, NH, BQ) { __builtin_amdgcn_s_setprio(1); \
    _Pragma("unroll") for (int mm_ = 0; mm_ < 3; ++mm_) \
        _Pragma("unroll") for (int nn_ = 0; nn_ < 2; ++nn_) { \
            acc[(MH)*3+mm_][(NH)*2+nn_] = MFMA16(aq[mm_][0], BQ[nn_][0], acc[(MH)*3+mm_][(NH)*2+nn_]); \
            acc[(MH)*3+mm_][(NH)*2+nn_] = MFMA16(aq[mm_][1], BQ[nn_][1], acc[(MH)*3+mm_][(NH)*2+nn_]); } \
    __builtin_amdgcn_s_setprio(0); }

#define SFENCE __builtin_amdgcn_sched_barrier(0)
#define WAITV4 { SFENCE; asm volatile("s_waitcnt vmcnt(4)"); SFENCE; }
#define WAITV0 { SFENCE; asm volatile("s_waitcnt vmcnt(0)"); SFENCE; }
#define BARR   { SFENCE; __builtin_amdgcn_s_barrier(); SFENCE; }

#define BUF1 57344

    // prologue: A(0),B(0) -> buf0; B(1) -> buf1 (11 issues). vmcnt(4): A(0)+B(0) landed,
    // B(1)'s 4 may fly. A(1) staged at j=0 P0/P1.
    STAGE(Ag, 0,            0, 0); STAGE(Ag, 0,            1, 0); STAGE(Ag, 0,            2, 0);
    STAGE(Bg, 24576,        0, 0); STAGE(Bg, 24576,        1, 0);
    STAGE(Bg, 24576,        2, 0); STAGE(Bg, 24576,        3, 0);
    STAGE(Bg, BUF1 + 24576, 0, 1); STAGE(Bg, BUF1 + 24576, 1, 1);
    STAGE(Bg, BUF1 + 24576, 2, 1); STAGE(Bg, BUF1 + 24576, 3, 1);
    WAITV4; BARR;

    for (int j = 0; j < NIT; ++j) {
        const int  t0 = 2 * j, t1 = 2 * j + 1;
        const bool lastj = (j == NIT - 1);

        // P0: (m0,n0) of tile t0 (buf0); stage A(t1)u0,u1 -> buf1
        READ_A(0, 0); READ_B(0, 0, bn0);
        STAGE(Ag, BUF1, 0, t1); STAGE(Ag, BUF1, 1, t1);
        BARR; MF(0, 0, bn0);
        // P1: (m0,n1); stage A(t1)u2
        READ_B(0, 1, bn1);
        STAGE(Ag, BUF1, 2, t1);
        BARR; MF(0, 1, bn1);
        // P2+P3 merged: (m1,n1)+(m1,n0); stage B(t0+2)u0-3; counted wait #1
        READ_A(0, 1);
        if (!lastj) { STAGE(Bg, 24576, 0, t0 + 2); STAGE(Bg, 24576, 1, t0 + 2);
                      STAGE(Bg, 24576, 2, t0 + 2); STAGE(Bg, 24576, 3, t0 + 2); WAITV4; }
        else        { WAITV0; }
        BARR; MF(1, 1, bn1); MF(1, 0, bn0);
        // P4: (m0,n0) of tile t1 (buf1); stage A(t0+2)u0,u1 -> buf0
        READ_A(BUF1, 0); READ_B(BUF1, 0, bn0);
        if (!lastj) { STAGE(Ag, 0, 0, t0 + 2); STAGE(Ag, 0, 1, t0 + 2); }
        BARR; MF(0, 0, bn0);
        // P5: (m0,n1); stage A(t0+2)u2
        READ_B(BUF1, 1, bn1);
        if (!lastj) STAGE(Ag, 0, 2, t0 + 2);
        BARR; MF(0, 1, bn1);
        // P6+P7 merged: (m1,n1)+(m1,n0); stage B(t1+2)u0-3; counted wait #2
        READ_A(BUF1, 1);
        if (!lastj) { STAGE(Bg, BUF1 + 24576, 0, t1 + 2); STAGE(Bg, BUF1 + 24576, 1, t1 + 2);
                      STAGE(Bg, BUF1 + 24576, 2, t1 + 2); STAGE(Bg, BUF1 + 24576, 3, t1 + 2);
                      WAITV4; }
        BARR; MF(1, 1, bn1); MF(1, 0, bn0);
    }
#undef STAGE
#undef READ_A
#undef READ_B
#undef MF
#undef SFENCE
#undef WAITV4
#undef WAITV0
#undef BARR
#undef BUF1

    // epilogue: C/D frag layout col=lane&15, row=(lane>>4)*4+r  [m89/m91]
    const int rg = (lane >> 4) << 2;
    #pragma unroll
    for (int nq = 0; nq < 4; ++nq) {
        const int col = tn * 256 + wn * 64 + (nq >> 1) * 32 + (nq & 1) * 16 + l16;
        const float sc = scale[col];
        const float bi = bias[col];
        #pragma unroll
        for (int mq = 0; mq < 6; ++mq) {
            const int row0 = tm * BM + wm * 96 + (mq / 3) * 48 + (mq % 3) * 16 + rg;
            #pragma unroll
            for (int rr = 0; rr < 4; ++rr) {
                float v = acc[mq][nq][rr] * sc + bi;
                if (EPI == 0) {
                    float g = 0.5f * v * (1.0f + erff(v * 0.70710678118654752f));
                    ((unsigned short*)Cout)[(size_t)(row0 + rr) * 4096 + col] = f2bf(g);
                } else {
                    ((float*)Cout)[(size_t)(row0 + rr) * 4096 + col] = v;
                }
            }
        }
    }
}

extern "C" void kernel_launch(void* const* d_in, const int* in_sizes, int n_in,
                              void* d_out, int out_size, void* d_ws, size_t ws_size,
                              hipStream_t stream) {
    const float* x   = (const float*)d_in[0];
    const int*   w1q = (const int*)d_in[1];
    const float* s1  = (const float*)d_in[2];
    const float* b1  = (const float*)d_in[3];
    const int*   w2q = (const int*)d_in[4];
    const float* s2  = (const float*)d_in[5];
    const float* b2  = (const float*)d_in[6];
    float*       out = (float*)d_out;

    // allow 112 KiB dynamic LDS (idempotent, not a stream op)
    hipFuncSetAttribute((const void*)gemm192<0>, hipFuncAttributeMaxDynamicSharedMemorySize, 114688);
    hipFuncSetAttribute((const void*)gemm192<1>, hipFuncAttributeMaxDynamicSharedMemorySize, 114688);

    char* ws = (char*)d_ws;
    const size_t XBF  = (size_t)NROWS   * IN_DIM  * 2;
    const size_t W1BF = (size_t)HID_DIM * IN_DIM  * 2;
    const size_t W2BF = (size_t)OUT_DIM * HID_DIM * 2;
    const size_t FIXED = XBF + W1BF + W2BF;

    unsigned short* xbf  = (unsigned short*)ws;
    unsigned short* w1bf = (unsigned short*)(ws + XBF);
    unsigned short* w2bf = (unsigned short*)(ws + XBF + W1BF);
    unsigned short* hbuf = (unsigned short*)(ws + FIXED);

    {
        int nvx = NROWS * IN_DIM / 8;
        cvt_f32_bf16_k<<<(nvx + 255) / 256, 256, 0, stream>>>((const float4*)x, (uint4*)xbf, nvx);
        int nv1 = HID_DIM * IN_DIM / 8;
        cvt_i32_bf16_k<<<(nv1 + 255) / 256, 256, 0, stream>>>((const int4*)w1q, (uint4*)w1bf, nv1);
        int nv2 = OUT_DIM * HID_DIM / 8;
        cvt_i32_bf16_k<<<(nv2 + 255) / 256, 256, 0, stream>>>((const int4*)w2q, (uint4*)w2bf, nv2);
    }

    // chunk M (multiples of BM) so h fits in remaining workspace
    size_t avail = (ws_size > FIXED) ? (ws_size - FIXED) : 0;
    long rp = (long)(avail / ((size_t)HID_DIM * 2));
    rp = (rp / BM) * BM;
    if (rp > NROWS) rp = NROWS;
    if (rp < BM)    rp = BM;

    for (int r0 = 0; r0 < NROWS; r0 += (int)rp) {
        int rows = (int)(((long)(NROWS - r0) < rp) ? (NROWS - r0) : rp);
        dim3 g(NTN * (rows / BM));
        gemm192<0><<<g, 512, 114688, stream>>>(xbf + (size_t)r0 * IN_DIM, w1bf, s1, b1,
                                               (void*)hbuf, IN_DIM);
        gemm192<1><<<g, 512, 114688, stream>>>(hbuf, w2bf, s2, b2,
                                               (void*)(out + (size_t)r0 * OUT_DIM), HID_DIM);
    }
    (void)in_sizes; (void)n_in; (void)out_size;
}

// Round 17
// 801.363 us; speedup vs baseline: 1.2339x; 1.0360x over previous
//
#include <hip/hip_runtime.h>
#include <math.h>

// Problem constants (from reference)
#define NROWS 18432
#define IN_DIM 1024
#define HID_DIM 4096
#define OUT_DIM 4096
#define NTN 16    // 4096/256 column tiles
#define BM  192   // 18432/192=96 -> 1536 blocks = exactly 6 rounds on 256 CUs (R14 win)

typedef __attribute__((ext_vector_type(8))) short bf16x8;
typedef __attribute__((ext_vector_type(4))) float f32x4;

typedef const __attribute__((address_space(1))) char gchar;
typedef __attribute__((address_space(3))) char lchar;

__device__ __forceinline__ unsigned short f2bf(float f) {
    union { float f; unsigned u; } v; v.f = f;
    unsigned r = v.u + 0x7fffu + ((v.u >> 16) & 1u);  // RNE
    return (unsigned short)(r >> 16);
}

__device__ __forceinline__ f32x4 MFMA16(bf16x8 a, bf16x8 b, f32x4 c) {
    return __builtin_amdgcn_mfma_f32_16x16x32_bf16(a, b, c, 0, 0, 0);
}

// ---------------- conversion kernels ----------------

__global__ void cvt_f32_bf16_k(const float4* __restrict__ in, uint4* __restrict__ out, int nvec) {
    int i = blockIdx.x * blockDim.x + threadIdx.x;
    if (i >= nvec) return;
    float4 a = in[2 * i], b = in[2 * i + 1];
    union { unsigned short s[8]; uint4 v; } o;
    o.s[0] = f2bf(a.x); o.s[1] = f2bf(a.y); o.s[2] = f2bf(a.z); o.s[3] = f2bf(a.w);
    o.s[4] = f2bf(b.x); o.s[5] = f2bf(b.y); o.s[6] = f2bf(b.z); o.s[7] = f2bf(b.w);
    out[i] = o.v;
}

// int8 values harness-materialized as int32; exact in bf16
__global__ void cvt_i32_bf16_k(const int4* __restrict__ in, uint4* __restrict__ out, int nvec) {
    int i = blockIdx.x * blockDim.x + threadIdx.x;
    if (i >= nvec) return;
    int4 a = in[2 * i], b = in[2 * i + 1];
    union { unsigned short s[8]; uint4 v; } o;
    o.s[0] = f2bf((float)a.x); o.s[1] = f2bf((float)a.y);
    o.s[2] = f2bf((float)a.z); o.s[3] = f2bf((float)a.w);
    o.s[4] = f2bf((float)b.x); o.s[5] = f2bf((float)b.y);
    o.s[6] = f2bf((float)b.z); o.s[7] = f2bf((float)b.w);
    out[i] = o.v;
}

// -------- 192x256 8-phase GEMM (R14: best measured, 802us, MfmaUtil 56.7%) --------
// R16's merged-phase variant regressed (830us, 48.6%): the 8-phase fine interleave is
// load-bearing. This is R14 verbatim.
// 8 waves (2Mx4N), per-wave 96x64 (acc[6][4]). LDS: 2 bufs x 56KB {A 24KB (3x8KB units),
// B 32KB (4x8KB units)}; buf0 @0 (even tiles), buf1 @57344 (odd tiles). BM=192 -> 1536
// blocks = exactly 6 full rounds on 256 CUs (zero tail; BM=256's 4.5 rounds wasted ~11%).
// Stage units/phase: {P0:A(b)u01, P1:A(b)u2, P2:B(a+2)u01, P3:B(a+2)u23, P4:A(a+2)u01,
// P5:A(a+2)u2, P6:B(b+2)u01, P7:B(b+2)u23} = 14/iter. Waits: vmcnt(4) @P3 (11 outstanding,
// newest4 = B(a+2); drains A(b)+B(b)) and @P7 (newest4 = B(b+2); drains tile a+2) -- verified
// steady-state + prologue (11 issues, vmcnt(4)) + tail (v0 @P3, no stages/wait after).
// WAR: every stage target dead >=1 barrier earlier. All stages uniform 16B x 512 threads
// (per-wave vmcnt counts identical).
// Swizzle: slot (ks*4+cgi)^(l16&7) on reads; inverse on stage source (rule 21); 0-conflict.
// EPI==0: bf16 gelu(acc*sc+bi); EPI==1: f32 acc*sc+bi. Output row-stride hardcoded 4096.
template<int EPI>
__global__ __launch_bounds__(512, 2)
void gemm192(const unsigned short* __restrict__ A, const unsigned short* __restrict__ B,
             const float* __restrict__ scale, const float* __restrict__ bias,
             void* __restrict__ Cout, int K) {
    extern __shared__ __align__(16) char sm[];   // 114688 bytes dynamic

    const int tid  = threadIdx.x;
    const int lane = tid & 63;
    const int wid  = tid >> 6;
    const int wm   = wid >> 2, wn = wid & 3;

    // T1: bijective XCD swizzle (m204); nwg = 1536 (multiple of 8)
    const int nwg  = gridDim.x;
    const int q    = nwg >> 3, r = nwg & 7;
    const int xcd  = blockIdx.x & 7, bidx = blockIdx.x >> 3;
    const int swz  = xcd * q + (xcd < r ? xcd : r) + bidx;
    const int tm   = swz / NTN, tn = swz % NTN;

    const size_t rowbytes = (size_t)K * 2;
    const char* Ag = (const char*)A + (size_t)tm * BM * rowbytes;
    const char* Bg = (const char*)B + (size_t)tn * 256 * rowbytes;

    const int l16 = lane & 15;
    const int cgi = lane >> 4;
    const int sw  = l16 & 7;
    const int c0  = ((cgi       ^ sw) << 4);   // swizzled byte-slot, k-step 0
    const int c1  = (((4 | cgi) ^ sw) << 4);   // swizzled byte-slot, k-step 1

    f32x4  acc[6][4] = {};
    bf16x8 aq[3][2], bn0[2][2], bn1[2][2];

    const int NIT = K >> 7;   // iterations (2 K-tiles of 64 each)

// stage one 8KB unit UN of region at LDSOFF (A: UN 0-2 covers rows 0-191; B: UN 0-3 rows 0-255)
// LDS dest linear; global source pre-inverse-swizzled (rule 21).
#define STAGE(GB, LDSOFF, UN, TILE) { \
    const int po_ = ((UN) << 13) + (tid << 4); \
    const int pr_ = po_ >> 7; \
    const int pc_ = (po_ & 127) ^ ((pr_ & 7) << 4); \
    __builtin_amdgcn_global_load_lds( \
        (gchar*)((GB) + (size_t)pr_ * rowbytes + ((size_t)(TILE) << 7) + (size_t)pc_), \
        (lchar*)(sm + (LDSOFF) + po_), 16, 0, 0); \
}

// A frags for 48-row quadrant MH: rows wm*96 + MH*48 + mm*16 + l16 (row&7 == l16&7)
#define READ_A(BUFOFF, MH) { const char* Ab_ = sm + (BUFOFF); \
    _Pragma("unroll") for (int mm_ = 0; mm_ < 3; ++mm_) { \
        const int ro_ = (wm * 96 + (MH) * 48 + mm_ * 16 + l16) << 7; \
        aq[mm_][0] = *(const bf16x8*)(Ab_ + ro_ + c0); \
        aq[mm_][1] = *(const bf16x8*)(Ab_ + ro_ + c1); } }

// B frags for 32-col half NH of this wave's 64-col strip
#define READ_B(BUFOFF, NH, DST) { const char* Bb_ = sm + (BUFOFF) + 24576; \
    _Pragma("unroll") for (int nn_ = 0; nn_ < 2; ++nn_) { \
        const int ro_ = ((wn >> 1) * 128 + (wn & 1) * 64 + (NH) * 32 + nn_ * 16 + l16) << 7; \
        DST[nn_][0] = *(const bf16x8*)(Bb_ + ro_ + c0); \
        DST[nn_][1] = *(const bf16x8*)(Bb_ + ro_ + c1); } }

// one quadrant x K=64: 3 mm x 2 nn x 2 ks = 12 MFMA
#define MF(MH, NH, BQ) { __builtin_amdgcn_s_setprio(1); \
    _Pragma("unroll") for (int mm_ = 0; mm_ < 3; ++mm_) \
        _Pragma("unroll") for (int nn_ = 0; nn_ < 2; ++nn_) { \
            acc[(MH)*3+mm_][(NH)*2+nn_] = MFMA16(aq[mm_][0], BQ[nn_][0], acc[(MH)*3+mm_][(NH)*2+nn_]); \
            acc[(MH)*3+mm_][(NH)*2+nn_] = MFMA16(aq[mm_][1], BQ[nn_][1], acc[(MH)*3+mm_][(NH)*2+nn_]); } \
    __builtin_amdgcn_s_setprio(0); }

#define SFENCE __builtin_amdgcn_sched_barrier(0)
#define WAITV4 { SFENCE; asm volatile("s_waitcnt vmcnt(4)"); SFENCE; }
#define WAITV0 { SFENCE; asm volatile("s_waitcnt vmcnt(0)"); SFENCE; }
#define BARR   { SFENCE; __builtin_amdgcn_s_barrier(); SFENCE; }

#define BUF1 57344

    // prologue: A(0),B(0) -> buf0; B(1) -> buf1 (11 issues). vmcnt(4): A(0)+B(0) landed,
    // B(1)'s 4 may fly. A(1) staged at j=0 P0/P1.
    STAGE(Ag, 0,            0, 0); STAGE(Ag, 0,            1, 0); STAGE(Ag, 0,            2, 0);
    STAGE(Bg, 24576,        0, 0); STAGE(Bg, 24576,        1, 0);
    STAGE(Bg, 24576,        2, 0); STAGE(Bg, 24576,        3, 0);
    STAGE(Bg, BUF1 + 24576, 0, 1); STAGE(Bg, BUF1 + 24576, 1, 1);
    STAGE(Bg, BUF1 + 24576, 2, 1); STAGE(Bg, BUF1 + 24576, 3, 1);
    WAITV4; BARR;

    for (int j = 0; j < NIT; ++j) {
        const int  t0 = 2 * j, t1 = 2 * j + 1;
        const bool lastj = (j == NIT - 1);   // note: (t0+2<NT) == (t1+2<NT) == !lastj

        // P0: (m0,n0) of tile t0 (buf0); stage A(t1)u0,u1 -> buf1
        READ_A(0, 0); READ_B(0, 0, bn0);
        STAGE(Ag, BUF1, 0, t1); STAGE(Ag, BUF1, 1, t1);
        BARR; MF(0, 0, bn0);
        // P1: (m0,n1); stage A(t1)u2
        READ_B(0, 1, bn1);
        STAGE(Ag, BUF1, 2, t1);
        BARR; MF(0, 1, bn1);
        // P2: (m1,n1); stage B(t0+2)u0,u1 -> buf0
        READ_A(0, 1);
        if (!lastj) { STAGE(Bg, 24576, 0, t0 + 2); STAGE(Bg, 24576, 1, t0 + 2); }
        BARR; MF(1, 1, bn1);
        // P3: (m1,n0); stage B(t0+2)u2,u3; counted wait #1 (drains A(t1)+B(t1))
        if (!lastj) { STAGE(Bg, 24576, 2, t0 + 2); STAGE(Bg, 24576, 3, t0 + 2); WAITV4; }
        else        { WAITV0; }
        BARR; MF(1, 0, bn0);
        // P4: (m0,n0) of tile t1 (buf1); stage A(t0+2)u0,u1 -> buf0
        READ_A(BUF1, 0); READ_B(BUF1, 0, bn0);
        if (!lastj) { STAGE(Ag, 0, 0, t0 + 2); STAGE(Ag, 0, 1, t0 + 2); }
        BARR; MF(0, 0, bn0);
        // P5: (m0,n1); stage A(t0+2)u2
        READ_B(BUF1, 1, bn1);
        if (!lastj) STAGE(Ag, 0, 2, t0 + 2);
        BARR; MF(0, 1, bn1);
        // P6: (m1,n1); stage B(t1+2)u0,u1 -> buf1
        READ_A(BUF1, 1);
        if (!lastj) { STAGE(Bg, BUF1 + 24576, 0, t1 + 2); STAGE(Bg, BUF1 + 24576, 1, t1 + 2); }
        BARR; MF(1, 1, bn1);
        // P7: (m1,n0); stage B(t1+2)u2,u3; counted wait #2 (drains tile t0+2)
        if (!lastj) { STAGE(Bg, BUF1 + 24576, 2, t1 + 2); STAGE(Bg, BUF1 + 24576, 3, t1 + 2);
                      WAITV4; }
        BARR; MF(1, 0, bn0);
    }
#undef STAGE
#undef READ_A
#undef READ_B
#undef MF
#undef SFENCE
#undef WAITV4
#undef WAITV0
#undef BARR
#undef BUF1

    // epilogue: C/D frag layout col=lane&15, row=(lane>>4)*4+r  [m89/m91]
    const int rg = (lane >> 4) << 2;
    #pragma unroll
    for (int nq = 0; nq < 4; ++nq) {
        const int col = tn * 256 + wn * 64 + (nq >> 1) * 32 + (nq & 1) * 16 + l16;
        const float sc = scale[col];
        const float bi = bias[col];
        #pragma unroll
        for (int mq = 0; mq < 6; ++mq) {
            const int row0 = tm * BM + wm * 96 + (mq / 3) * 48 + (mq % 3) * 16 + rg;
            #pragma unroll
            for (int rr = 0; rr < 4; ++rr) {
                float v = acc[mq][nq][rr] * sc + bi;
                if (EPI == 0) {
                    float g = 0.5f * v * (1.0f + erff(v * 0.70710678118654752f));
                    ((unsigned short*)Cout)[(size_t)(row0 + rr) * 4096 + col] = f2bf(g);
                } else {
                    ((float*)Cout)[(size_t)(row0 + rr) * 4096 + col] = v;
                }
            }
        }
    }
}

extern "C" void kernel_launch(void* const* d_in, const int* in_sizes, int n_in,
                              void* d_out, int out_size, void* d_ws, size_t ws_size,
                              hipStream_t stream) {
    const float* x   = (const float*)d_in[0];
    const int*   w1q = (const int*)d_in[1];
    const float* s1  = (const float*)d_in[2];
    const float* b1  = (const float*)d_in[3];
    const int*   w2q = (const int*)d_in[4];
    const float* s2  = (const float*)d_in[5];
    const float* b2  = (const float*)d_in[6];
    float*       out = (float*)d_out;

    // allow 112 KiB dynamic LDS (idempotent, not a stream op)
    hipFuncSetAttribute((const void*)gemm192<0>, hipFuncAttributeMaxDynamicSharedMemorySize, 114688);
    hipFuncSetAttribute((const void*)gemm192<1>, hipFuncAttributeMaxDynamicSharedMemorySize, 114688);

    char* ws = (char*)d_ws;
    const size_t XBF  = (size_t)NROWS   * IN_DIM  * 2;
    const size_t W1BF = (size_t)HID_DIM * IN_DIM  * 2;
    const size_t W2BF = (size_t)OUT_DIM * HID_DIM * 2;
    const size_t FIXED = XBF + W1BF + W2BF;

    unsigned short* xbf  = (unsigned short*)ws;
    unsigned short* w1bf = (unsigned short*)(ws + XBF);
    unsigned short* w2bf = (unsigned short*)(ws + XBF + W1BF);
    unsigned short* hbuf = (unsigned short*)(ws + FIXED);

    {
        int nvx = NROWS * IN_DIM / 8;
        cvt_f32_bf16_k<<<(nvx + 255) / 256, 256, 0, stream>>>((const float4*)x, (uint4*)xbf, nvx);
        int nv1 = HID_DIM * IN_DIM / 8;
        cvt_i32_bf16_k<<<(nv1 + 255) / 256, 256, 0, stream>>>((const int4*)w1q, (uint4*)w1bf, nv1);
        int nv2 = OUT_DIM * HID_DIM / 8;
        cvt_i32_bf16_k<<<(nv2 + 255) / 256, 256, 0, stream>>>((const int4*)w2q, (uint4*)w2bf, nv2);
    }

    // chunk M (multiples of BM) so h fits in remaining workspace
    size_t avail = (ws_size > FIXED) ? (ws_size - FIXED) : 0;
    long rp = (long)(avail / ((size_t)HID_DIM * 2));
    rp = (rp / BM) * BM;
    if (rp > NROWS) rp = NROWS;
    if (rp < BM)    rp = BM;

    for (int r0 = 0; r0 < NROWS; r0 += (int)rp) {
        int rows = (int)(((long)(NROWS - r0) < rp) ? (NROWS - r0) : rp);
        dim3 g(NTN * (rows / BM));
        gemm192<0><<<g, 512, 114688, stream>>>(xbf + (size_t)r0 * IN_DIM, w1bf, s1, b1,
                                               (void*)hbuf, IN_DIM);
        gemm192<1><<<g, 512, 114688, stream>>>(hbuf, w2bf, s2, b2,
                                               (void*)(out + (size_t)r0 * OUT_DIM), HID_DIM);
    }
    (void)in_sizes; (void)n_in; (void)out_size;
}

// Round 18
// 754.979 us; speedup vs baseline: 1.3097x; 1.0614x over previous
//
#include <hip/hip_runtime.h>
#include <math.h>

// Problem constants (from reference)
#define NROWS 18432
#define IN_DIM 1024
#define HID_DIM 4096
#define OUT_DIM 4096
#define NTN 16    // 4096/256 column tiles
#define BM  192   // 18432/192=96 -> 1536 blocks = exactly 6 rounds on 256 CUs (R14 win)

typedef __attribute__((ext_vector_type(8))) short bf16x8;
typedef __attribute__((ext_vector_type(4))) float f32x4;

typedef const __attribute__((address_space(1))) char gchar;
typedef __attribute__((address_space(3))) char lchar;

__device__ __forceinline__ unsigned short f2bf(float f) {
    union { float f; unsigned u; } v; v.f = f;
    unsigned r = v.u + 0x7fffu + ((v.u >> 16) & 1u);  // RNE
    return (unsigned short)(r >> 16);
}

__device__ __forceinline__ f32x4 MFMA16(bf16x8 a, bf16x8 b, f32x4 c) {
    return __builtin_amdgcn_mfma_f32_16x16x32_bf16(a, b, c, 0, 0, 0);
}

// ---------------- conversion kernels ----------------

__global__ void cvt_f32_bf16_k(const float4* __restrict__ in, uint4* __restrict__ out, int nvec) {
    int i = blockIdx.x * blockDim.x + threadIdx.x;
    if (i >= nvec) return;
    float4 a = in[2 * i], b = in[2 * i + 1];
    union { unsigned short s[8]; uint4 v; } o;
    o.s[0] = f2bf(a.x); o.s[1] = f2bf(a.y); o.s[2] = f2bf(a.z); o.s[3] = f2bf(a.w);
    o.s[4] = f2bf(b.x); o.s[5] = f2bf(b.y); o.s[6] = f2bf(b.z); o.s[7] = f2bf(b.w);
    out[i] = o.v;
}

// int8 values harness-materialized as int32; exact in bf16
__global__ void cvt_i32_bf16_k(const int4* __restrict__ in, uint4* __restrict__ out, int nvec) {
    int i = blockIdx.x * blockDim.x + threadIdx.x;
    if (i >= nvec) return;
    int4 a = in[2 * i], b = in[2 * i + 1];
    union { unsigned short s[8]; uint4 v; } o;
    o.s[0] = f2bf((float)a.x); o.s[1] = f2bf((float)a.y);
    o.s[2] = f2bf((float)a.z); o.s[3] = f2bf((float)a.w);
    o.s[4] = f2bf((float)b.x); o.s[5] = f2bf((float)b.y);
    o.s[6] = f2bf((float)b.z); o.s[7] = f2bf((float)b.w);
    out[i] = o.v;
}

// -------- 192x256 8-phase GEMM (R14 structure, best measured: 802/801us, MfmaUtil 55-57) ----
// Delta vs R17: EPI==1 output uses __builtin_nontemporal_store (nt cache policy).
// Rationale: layer-2 FETCH_SIZE = 1.0-1.6 GB vs ~185 MB unique (h 151 + w2 34, which FIT the
// 256MB L3); the 302 MB/dispatch of out-writes stream through L2/L3 with write-allocate,
// evicting the h/w2 read-set. nt store bypasses cache allocation for the never-re-read output.
// h (EPI==0) keeps normal stores -- layer-2 re-reads it; its L3 residency is what we protect.
// Everything else identical to R14 (see its ledger comments): 8 waves (2Mx4N), per-wave 96x64,
// LDS 2x56KB, stage 14 units/iter, waits vmcnt(4)@P3/P7 (tail v0@P3), swizzle
// slot=(ks*4+cgi)^(l16&7) + inverse on stage source, T1 XCD swizzle, T5 setprio, BM=192
// zero-tail grid. EPI==0: bf16 gelu(acc*sc+bi); EPI==1: f32 acc*sc+bi. C row-stride 4096.
template<int EPI>
__global__ __launch_bounds__(512, 2)
void gemm192(const unsigned short* __restrict__ A, const unsigned short* __restrict__ B,
             const float* __restrict__ scale, const float* __restrict__ bias,
             void* __restrict__ Cout, int K) {
    extern __shared__ __align__(16) char sm[];   // 114688 bytes dynamic

    const int tid  = threadIdx.x;
    const int lane = tid & 63;
    const int wid  = tid >> 6;
    const int wm   = wid >> 2, wn = wid & 3;

    // T1: bijective XCD swizzle (m204); nwg = 1536 (multiple of 8)
    const int nwg  = gridDim.x;
    const int q    = nwg >> 3, r = nwg & 7;
    const int xcd  = blockIdx.x & 7, bidx = blockIdx.x >> 3;
    const int swz  = xcd * q + (xcd < r ? xcd : r) + bidx;
    const int tm   = swz / NTN, tn = swz % NTN;

    const size_t rowbytes = (size_t)K * 2;
    const char* Ag = (const char*)A + (size_t)tm * BM * rowbytes;
    const char* Bg = (const char*)B + (size_t)tn * 256 * rowbytes;

    const int l16 = lane & 15;
    const int cgi = lane >> 4;
    const int sw  = l16 & 7;
    const int c0  = ((cgi       ^ sw) << 4);   // swizzled byte-slot, k-step 0
    const int c1  = (((4 | cgi) ^ sw) << 4);   // swizzled byte-slot, k-step 1

    f32x4  acc[6][4] = {};
    bf16x8 aq[3][2], bn0[2][2], bn1[2][2];

    const int NIT = K >> 7;   // iterations (2 K-tiles of 64 each)

// stage one 8KB unit UN of region at LDSOFF (A: UN 0-2 covers rows 0-191; B: UN 0-3 rows 0-255)
// LDS dest linear; global source pre-inverse-swizzled (rule 21).
#define STAGE(GB, LDSOFF, UN, TILE) { \
    const int po_ = ((UN) << 13) + (tid << 4); \
    const int pr_ = po_ >> 7; \
    const int pc_ = (po_ & 127) ^ ((pr_ & 7) << 4); \
    __builtin_amdgcn_global_load_lds( \
        (gchar*)((GB) + (size_t)pr_ * rowbytes + ((size_t)(TILE) << 7) + (size_t)pc_), \
        (lchar*)(sm + (LDSOFF) + po_), 16, 0, 0); \
}

// A frags for 48-row quadrant MH: rows wm*96 + MH*48 + mm*16 + l16 (row&7 == l16&7)
#define READ_A(BUFOFF, MH) { const char* Ab_ = sm + (BUFOFF); \
    _Pragma("unroll") for (int mm_ = 0; mm_ < 3; ++mm_) { \
        const int ro_ = (wm * 96 + (MH) * 48 + mm_ * 16 + l16) << 7; \
        aq[mm_][0] = *(const bf16x8*)(Ab_ + ro_ + c0); \
        aq[mm_][1] = *(const bf16x8*)(Ab_ + ro_ + c1); } }

// B frags for 32-col half NH of this wave's 64-col strip
#define READ_B(BUFOFF, NH, DST) { const char* Bb_ = sm + (BUFOFF) + 24576; \
    _Pragma("unroll") for (int nn_ = 0; nn_ < 2; ++nn_) { \
        const int ro_ = ((wn >> 1) * 128 + (wn & 1) * 64 + (NH) * 32 + nn_ * 16 + l16) << 7; \
        DST[nn_][0] = *(const bf16x8*)(Bb_ + ro_ + c0); \
        DST[nn_][1] = *(const bf16x8*)(Bb_ + ro_ + c1); } }

// one quadrant x K=64: 3 mm x 2 nn x 2 ks = 12 MFMA
#define MF(MH, NH, BQ) { __builtin_amdgcn_s_setprio(1); \
    _Pragma("unroll") for (int mm_ = 0; mm_ < 3; ++mm_) \
        _Pragma("unroll") for (int nn_ = 0; nn_ < 2; ++nn_) { \
            acc[(MH)*3+mm_][(NH)*2+nn_] = MFMA16(aq[mm_][0], BQ[nn_][0], acc[(MH)*3+mm_][(NH)*2+nn_]); \
            acc[(MH)*3+mm_][(NH)*2+nn_] = MFMA16(aq[mm_][1], BQ[nn_][1], acc[(MH)*3+mm_][(NH)*2+nn_]); } \
    __builtin_amdgcn_s_setprio(0); }

#define SFENCE __builtin_amdgcn_sched_barrier(0)
#define WAITV4 { SFENCE; asm volatile("s_waitcnt vmcnt(4)"); SFENCE; }
#define WAITV0 { SFENCE; asm volatile("s_waitcnt vmcnt(0)"); SFENCE; }
#define BARR   { SFENCE; __builtin_amdgcn_s_barrier(); SFENCE; }

#define BUF1 57344

    // prologue: A(0),B(0) -> buf0; B(1) -> buf1 (11 issues). vmcnt(4): A(0)+B(0) landed,
    // B(1)'s 4 may fly. A(1) staged at j=0 P0/P1.
    STAGE(Ag, 0,            0, 0); STAGE(Ag, 0,            1, 0); STAGE(Ag, 0,            2, 0);
    STAGE(Bg, 24576,        0, 0); STAGE(Bg, 24576,        1, 0);
    STAGE(Bg, 24576,        2, 0); STAGE(Bg, 24576,        3, 0);
    STAGE(Bg, BUF1 + 24576, 0, 1); STAGE(Bg, BUF1 + 24576, 1, 1);
    STAGE(Bg, BUF1 + 24576, 2, 1); STAGE(Bg, BUF1 + 24576, 3, 1);
    WAITV4; BARR;

    for (int j = 0; j < NIT; ++j) {
        const int  t0 = 2 * j, t1 = 2 * j + 1;
        const bool lastj = (j == NIT - 1);   // note: (t0+2<NT) == (t1+2<NT) == !lastj

        // P0: (m0,n0) of tile t0 (buf0); stage A(t1)u0,u1 -> buf1
        READ_A(0, 0); READ_B(0, 0, bn0);
        STAGE(Ag, BUF1, 0, t1); STAGE(Ag, BUF1, 1, t1);
        BARR; MF(0, 0, bn0);
        // P1: (m0,n1); stage A(t1)u2
        READ_B(0, 1, bn1);
        STAGE(Ag, BUF1, 2, t1);
        BARR; MF(0, 1, bn1);
        // P2: (m1,n1); stage B(t0+2)u0,u1 -> buf0
        READ_A(0, 1);
        if (!lastj) { STAGE(Bg, 24576, 0, t0 + 2); STAGE(Bg, 24576, 1, t0 + 2); }
        BARR; MF(1, 1, bn1);
        // P3: (m1,n0); stage B(t0+2)u2,u3; counted wait #1 (drains A(t1)+B(t1))
        if (!lastj) { STAGE(Bg, 24576, 2, t0 + 2); STAGE(Bg, 24576, 3, t0 + 2); WAITV4; }
        else        { WAITV0; }
        BARR; MF(1, 0, bn0);
        // P4: (m0,n0) of tile t1 (buf1); stage A(t0+2)u0,u1 -> buf0
        READ_A(BUF1, 0); READ_B(BUF1, 0, bn0);
        if (!lastj) { STAGE(Ag, 0, 0, t0 + 2); STAGE(Ag, 0, 1, t0 + 2); }
        BARR; MF(0, 0, bn0);
        // P5: (m0,n1); stage A(t0+2)u2
        READ_B(BUF1, 1, bn1);
        if (!lastj) STAGE(Ag, 0, 2, t0 + 2);
        BARR; MF(0, 1, bn1);
        // P6: (m1,n1); stage B(t1+2)u0,u1 -> buf1
        READ_A(BUF1, 1);
        if (!lastj) { STAGE(Bg, BUF1 + 24576, 0, t1 + 2); STAGE(Bg, BUF1 + 24576, 1, t1 + 2); }
        BARR; MF(1, 1, bn1);
        // P7: (m1,n0); stage B(t1+2)u2,u3; counted wait #2 (drains tile t0+2)
        if (!lastj) { STAGE(Bg, BUF1 + 24576, 2, t1 + 2); STAGE(Bg, BUF1 + 24576, 3, t1 + 2);
                      WAITV4; }
        BARR; MF(1, 0, bn0);
    }
#undef STAGE
#undef READ_A
#undef READ_B
#undef MF
#undef SFENCE
#undef WAITV4
#undef WAITV0
#undef BARR
#undef BUF1

    // epilogue: C/D frag layout col=lane&15, row=(lane>>4)*4+r  [m89/m91]
    // EPI==1 (final out, never re-read): nontemporal stores -- bypass L2/L3 allocation so the
    // 302 MB write stream stops evicting the h/w2 read-set from L3 (FETCH_SIZE anomaly).
    const int rg = (lane >> 4) << 2;
    #pragma unroll
    for (int nq = 0; nq < 4; ++nq) {
        const int col = tn * 256 + wn * 64 + (nq >> 1) * 32 + (nq & 1) * 16 + l16;
        const float sc = scale[col];
        const float bi = bias[col];
        #pragma unroll
        for (int mq = 0; mq < 6; ++mq) {
            const int row0 = tm * BM + wm * 96 + (mq / 3) * 48 + (mq % 3) * 16 + rg;
            #pragma unroll
            for (int rr = 0; rr < 4; ++rr) {
                float v = acc[mq][nq][rr] * sc + bi;
                if (EPI == 0) {
                    float g = 0.5f * v * (1.0f + erff(v * 0.70710678118654752f));
                    ((unsigned short*)Cout)[(size_t)(row0 + rr) * 4096 + col] = f2bf(g);
                } else {
                    __builtin_nontemporal_store(
                        v, &((float*)Cout)[(size_t)(row0 + rr) * 4096 + col]);
                }
            }
        }
    }
}

extern "C" void kernel_launch(void* const* d_in, const int* in_sizes, int n_in,
                              void* d_out, int out_size, void* d_ws, size_t ws_size,
                              hipStream_t stream) {
    const float* x   = (const float*)d_in[0];
    const int*   w1q = (const int*)d_in[1];
    const float* s1  = (const float*)d_in[2];
    const float* b1  = (const float*)d_in[3];
    const int*   w2q = (const int*)d_in[4];
    const float* s2  = (const float*)d_in[5];
    const float* b2  = (const float*)d_in[6];
    float*       out = (float*)d_out;

    // allow 112 KiB dynamic LDS (idempotent, not a stream op)
    hipFuncSetAttribute((const void*)gemm192<0>, hipFuncAttributeMaxDynamicSharedMemorySize, 114688);
    hipFuncSetAttribute((const void*)gemm192<1>, hipFuncAttributeMaxDynamicSharedMemorySize, 114688);

    char* ws = (char*)d_ws;
    const size_t XBF  = (size_t)NROWS   * IN_DIM  * 2;
    const size_t W1BF = (size_t)HID_DIM * IN_DIM  * 2;
    const size_t W2BF = (size_t)OUT_DIM * HID_DIM * 2;
    const size_t FIXED = XBF + W1BF + W2BF;

    unsigned short* xbf  = (unsigned short*)ws;
    unsigned short* w1bf = (unsigned short*)(ws + XBF);
    unsigned short* w2bf = (unsigned short*)(ws + XBF + W1BF);
    unsigned short* hbuf = (unsigned short*)(ws + FIXED);

    {
        int nvx = NROWS * IN_DIM / 8;
        cvt_f32_bf16_k<<<(nvx + 255) / 256, 256, 0, stream>>>((const float4*)x, (uint4*)xbf, nvx);
        int nv1 = HID_DIM * IN_DIM / 8;
        cvt_i32_bf16_k<<<(nv1 + 255) / 256, 256, 0, stream>>>((const int4*)w1q, (uint4*)w1bf, nv1);
        int nv2 = OUT_DIM * HID_DIM / 8;
        cvt_i32_bf16_k<<<(nv2 + 255) / 256, 256, 0, stream>>>((const int4*)w2q, (uint4*)w2bf, nv2);
    }

    // chunk M (multiples of BM) so h fits in remaining workspace
    size_t avail = (ws_size > FIXED) ? (ws_size - FIXED) : 0;
    long rp = (long)(avail / ((size_t)HID_DIM * 2));
    rp = (rp / BM) * BM;
    if (rp > NROWS) rp = NROWS;
    if (rp < BM)    rp = BM;

    for (int r0 = 0; r0 < NROWS; r0 += (int)rp) {
        int rows = (int)(((long)(NROWS - r0) < rp) ? (NROWS - r0) : rp);
        dim3 g(NTN * (rows / BM));
        gemm192<0><<<g, 512, 114688, stream>>>(xbf + (size_t)r0 * IN_DIM, w1bf, s1, b1,
                                               (void*)hbuf, IN_DIM);
        gemm192<1><<<g, 512, 114688, stream>>>(hbuf, w2bf, s2, b2,
                                               (void*)(out + (size_t)r0 * OUT_DIM), HID_DIM);
    }
    (void)in_sizes; (void)n_in; (void)out_size;
}